// Round 15
// baseline (309.393 us; speedup 1.0000x reference)
//
#include <hip/hip_runtime.h>
#include <hip/hip_bf16.h>

#define EMB 768
#define NH 8
#define DH 96
#define BATCH 8
#define SEQ 1024
#define M_TOT (BATCH * SEQ)   // 8192 rows of x
#define NCOLS (3 * EMB)       // q(768) | k(768) | v(768) output channels

typedef float f32x4 __attribute__((ext_vector_type(4)));
typedef __bf16 bf16x8 __attribute__((ext_vector_type(8)));

__device__ __forceinline__ unsigned short f2bf_bits(float f) {
  __hip_bfloat16 b = __float2bfloat16(f);
  return *reinterpret_cast<unsigned short*>(&b);
}

__device__ __forceinline__ void gload_lds16(const void* g, void* l) {
  // async global->LDS, 16B per lane; LDS dest is wave-uniform base (+lane*16 by HW)
  __builtin_amdgcn_global_load_lds(
      (__attribute__((address_space(1))) void*)(g),
      (__attribute__((address_space(3))) void*)(l), 16, 0, 0);
}

// ---------------- prep: x fp32 -> bf16 ----------------
__global__ void prep_x_kernel(const float* __restrict__ x, __hip_bfloat16* __restrict__ xb) {
  const int n4 = M_TOT * EMB / 4;
  int i = blockIdx.x * blockDim.x + threadIdx.x;
  if (i < n4) {
    f32x4 v = reinterpret_cast<const f32x4*>(x)[i];
    ushort4 o;
    o.x = f2bf_bits(v[0]);
    o.y = f2bf_bits(v[1]);
    o.z = f2bf_bits(v[2]);
    o.w = f2bf_bits(v[3]);
    reinterpret_cast<ushort4*>(xb)[i] = o;
  }
}

// ---------------- prep: permuted weights -> bf16, bias fp32 ----------------
__global__ void prep_w_kernel(const float* __restrict__ qkv_w, const float* __restrict__ qkv_b,
                              const float* __restrict__ val_w, const float* __restrict__ val_b,
                              __hip_bfloat16* __restrict__ Wall, float* __restrict__ bias) {
  const float inv_s = 0.03608439182435161f;  // 1/sqrt(768)
  int idx = blockIdx.x * 256 + threadIdx.x;
  if (idx >= NCOLS * EMB) return;
  int r = idx / EMB;
  int c = idx - r * EMB;
  float v;
  if (r < EMB) {
    int h = r / DH, d = r - h * DH;
    int src = h * 192 + 2 * d;
    v = qkv_w[(size_t)src * EMB + c] * inv_s;
    if (c == 0) bias[r] = qkv_b[src] * inv_s;
  } else if (r < 2 * EMB) {
    int r2 = r - EMB;
    int h = r2 / DH, d = r2 - h * DH;
    int src = h * 192 + 2 * d + 1;
    v = qkv_w[(size_t)src * EMB + c];
    if (c == 0) bias[r] = qkv_b[src];
  } else {
    int r3 = r - 2 * EMB;
    v = val_w[(size_t)r3 * EMB + c];
    if (c == 0) bias[r] = val_b[r3];
  }
  Wall[idx] = __float2bfloat16(v);
}

// ---------------- fused projection GEMM (m97-structure, 128x128, BK=32) ----------------
// Byte-identical to r11 (2D grid, plain stores; q/k via padded-LDS head-packed epilogue).
__global__ __launch_bounds__(256) void gemm_kernel(
    const __hip_bfloat16* __restrict__ xb, const __hip_bfloat16* __restrict__ Wall,
    const float* __restrict__ bias, __hip_bfloat16* __restrict__ qhead,
    __hip_bfloat16* __restrict__ khead, float* __restrict__ vout) {
  __shared__ __hip_bfloat16 As[128 * 32];
  __shared__ __hip_bfloat16 Bs[128 * 32];
  __shared__ __hip_bfloat16 Cs[128][136];  // +8 pad, rows 16B-aligned
  const int tid = threadIdx.x;
  const int w = tid >> 6, l = tid & 63;
  const int m0 = blockIdx.x * 128;
  const int n0 = blockIdx.y * 128;
  const int wr = w >> 1, wc = w & 1;

  f32x4 acc[4][4] = {};

  const int sr0 = (w * 2 + 0) * 16 + (l >> 2);
  const int sr1 = (w * 2 + 1) * 16 + (l >> 2);
  const int sc = (l & 3) * 8;

  for (int kt = 0; kt < EMB / 32; ++kt) {
    const int k0 = kt * 32;
    gload_lds16(xb + (size_t)(m0 + sr0) * EMB + k0 + sc, (void*)(As + (w * 2 + 0) * 512));
    gload_lds16(xb + (size_t)(m0 + sr1) * EMB + k0 + sc, (void*)(As + (w * 2 + 1) * 512));
    gload_lds16(Wall + (size_t)(n0 + sr0) * EMB + k0 + sc, (void*)(Bs + (w * 2 + 0) * 512));
    gload_lds16(Wall + (size_t)(n0 + sr1) * EMB + k0 + sc, (void*)(Bs + (w * 2 + 1) * 512));
    __syncthreads();

    bf16x8 af[4], bfr[4];
#pragma unroll
    for (int t = 0; t < 4; ++t) {
      af[t] = *reinterpret_cast<const bf16x8*>(As + (wr * 64 + t * 16 + (l & 15)) * 32 + (l >> 4) * 8);
      bfr[t] = *reinterpret_cast<const bf16x8*>(Bs + (wc * 64 + t * 16 + (l & 15)) * 32 + (l >> 4) * 8);
    }
#pragma unroll
    for (int i = 0; i < 4; ++i)
#pragma unroll
      for (int j = 0; j < 4; ++j)
        acc[i][j] = __builtin_amdgcn_mfma_f32_16x16x32_bf16(af[i], bfr[j], acc[i][j], 0, 0, 0);
    __syncthreads();
  }

  if (n0 >= 2 * EMB) {
    const int rowbase = m0 + wr * 64;
    const int colbase = n0 - 2 * EMB + wc * 64;
#pragma unroll
    for (int j = 0; j < 4; ++j) {
      const int n = colbase + j * 16 + (l & 15);
      const float bb = bias[2 * EMB + n];
#pragma unroll
      for (int i = 0; i < 4; ++i) {
#pragma unroll
        for (int q = 0; q < 4; ++q) {
          const int m = rowbase + i * 16 + (l >> 4) * 4 + q;
          vout[(size_t)m * EMB + n] = acc[i][j][q] + bb;
        }
      }
    }
  } else {
#pragma unroll
    for (int j = 0; j < 4; ++j) {
      const int nl = wc * 64 + j * 16 + (l & 15);
      const float bb = bias[n0 + nl];
#pragma unroll
      for (int i = 0; i < 4; ++i) {
#pragma unroll
        for (int q = 0; q < 4; ++q) {
          const int ml = wr * 64 + i * 16 + (l >> 4) * 4 + q;
          Cs[ml][nl] = __float2bfloat16(acc[i][j][q] + bb);
        }
      }
    }
    __syncthreads();
    __hip_bfloat16* dst = (n0 >= EMB) ? khead : qhead;
    const int ch0 = (n0 >= EMB) ? (n0 - EMB) : n0;
    const int cg = (tid & 15) * 8;
    const int gch = ch0 + cg;
    const int hh = gch / DH, dd = gch - hh * DH;
#pragma unroll
    for (int pass = 0; pass < 8; ++pass) {
      const int r = pass * 16 + (tid >> 4);
      const int m = m0 + r;
      const int bb_ = m >> 10, mm = m & 1023;
      bf16x8 v8 = *reinterpret_cast<const bf16x8*>(&Cs[r][cg]);
      *reinterpret_cast<bf16x8*>(dst + ((size_t)(bb_ * NH + hh) * SEQ + mm) * DH + dd) = v8;
    }
  }
}

// ---------------- fused QK^T + softmax: r11-exact EXCEPT plain (non-nt) stores ----------------
// Grid 4096 (8 b-variants sharing rel rows co-XCD). 512 thr = 8 waves; block = 16 rows
// x 1024 cols; wave w owns contiguous cols [w*128, +128). K staged per-wave ring-3,
// counted vmcnt(6/3/0). A/B vs r11: stores go through L2 (write-combining merges the
// per-instruction 64B row-segments into full 128B lines before eviction).
__global__ __launch_bounds__(512, 2) void attn_kernel(
    const __hip_bfloat16* __restrict__ qhead, const __hip_bfloat16* __restrict__ khead,
    const float* __restrict__ rel, float* __restrict__ eout) {
  __shared__ alignas(16) char KS[8 * 3 * 3072];  // 73728 B: 8 waves x ring of 3
  __shared__ float redm[16][8];
  __shared__ float reds[16][8];

  const int t = threadIdx.x;
  const int w = t >> 6, l = t & 63;
  const int lr = l >> 4, lc = l & 15;
  const int flat = blockIdx.x;
  const int u = flat >> 6;
  const int b = (flat >> 3) & 7;
  const int g = u * 8 + (flat & 7);
  const int h = g >> 6;
  const int rb = g & 63;
  const int row0 = rb * 16;
  const size_t bh = (size_t)(b * NH + h);

  const __hip_bfloat16* qsrc = qhead + (bh * SEQ + row0 + lc) * DH;
  bf16x8 qf[3];
#pragma unroll
  for (int kc = 0; kc < 3; ++kc)
    qf[kc] = *reinterpret_cast<const bf16x8*>(qsrc + kc * 32 + lr * 8);

  const float* relsrc = rel + ((size_t)h * SEQ + row0 + lc) * SEQ + w * 128 + lr * 4;
  f32x4 relv[8];
#pragma unroll
  for (int s = 0; s < 8; ++s)
    relv[s] = *reinterpret_cast<const f32x4*>(relsrc + s * 16);

  const __hip_bfloat16* ksrc = khead + bh * SEQ * DH + (size_t)w * 128 * DH;
  char* kdst = KS + w * 9216;

#define STAGE_K(s, buf)                                                             \
  {                                                                                 \
    const __hip_bfloat16* s_ = ksrc + (size_t)(s) * 1536 + (size_t)l * 8;           \
    gload_lds16(s_, kdst + (buf) * 3072);                                           \
    gload_lds16(s_ + 512, kdst + (buf) * 3072 + 1024);                              \
    gload_lds16(s_ + 1024, kdst + (buf) * 3072 + 2048);                             \
  }

  STAGE_K(0, 0)
  STAGE_K(1, 1)

  f32x4 acc[8];
#pragma unroll
  for (int s = 0; s < 8; ++s) {
    if (s < 6) STAGE_K(s + 2, (s + 2) % 3)
    if (s < 6) {
      asm volatile("s_waitcnt vmcnt(6)" ::: "memory");
    } else if (s == 6) {
      asm volatile("s_waitcnt vmcnt(3)" ::: "memory");
    } else {
      asm volatile("s_waitcnt vmcnt(0)" ::: "memory");
    }
    __builtin_amdgcn_sched_barrier(0);
    const __hip_bfloat16* kp =
        reinterpret_cast<const __hip_bfloat16*>(kdst + (s % 3) * 3072) + lc * DH;
    f32x4 a = {0.f, 0.f, 0.f, 0.f};
    __builtin_amdgcn_s_setprio(1);
#pragma unroll
    for (int kc = 0; kc < 3; ++kc) {
      bf16x8 kf = *reinterpret_cast<const bf16x8*>(kp + kc * 32 + lr * 8);
      a = __builtin_amdgcn_mfma_f32_16x16x32_bf16(kf, qf[kc], a, 0, 0, 0);
    }
    __builtin_amdgcn_s_setprio(0);
    acc[s] = a + relv[s];
  }
#undef STAGE_K

  float mx = -3.4e38f;
#pragma unroll
  for (int s = 0; s < 8; ++s)
    mx = fmaxf(mx, fmaxf(fmaxf(acc[s][0], acc[s][1]), fmaxf(acc[s][2], acc[s][3])));
  mx = fmaxf(mx, __shfl_xor(mx, 16));
  mx = fmaxf(mx, __shfl_xor(mx, 32));
  if (l < 16) redm[lc][w] = mx;
  __syncthreads();
  float M = redm[lc][0];
#pragma unroll
  for (int i = 1; i < 8; ++i) M = fmaxf(M, redm[lc][i]);

  float sm = 0.f;
#pragma unroll
  for (int s = 0; s < 8; ++s) {
#pragma unroll
    for (int j = 0; j < 4; ++j) {
      float e = __expf(acc[s][j] - M);
      acc[s][j] = e;
      sm += e;
    }
  }
  sm += __shfl_xor(sm, 16);
  sm += __shfl_xor(sm, 32);
  if (l < 16) reds[lc][w] = sm;
  __syncthreads();
  float S = 0.f;
#pragma unroll
  for (int i = 0; i < 8; ++i) S += reds[lc][i];
  const float rinv = 1.0f / S;

  // plain stores (A/B vs r11's non-temporal): let L2 merge 64B segments into lines
  float* op = eout + (bh * SEQ + row0 + lc) * SEQ + w * 128 + lr * 4;
#pragma unroll
  for (int s = 0; s < 8; ++s) {
    f32x4 v = acc[s] * rinv;
    *reinterpret_cast<f32x4*>(op + s * 16) = v;
  }
}

extern "C" void kernel_launch(void* const* d_in, const int* in_sizes, int n_in,
                              void* d_out, int out_size, void* d_ws, size_t ws_size,
                              hipStream_t stream) {
  const float* x = (const float*)d_in[0];
  const float* rel = (const float*)d_in[1];
  const float* qkv_w = (const float*)d_in[2];
  const float* qkv_b = (const float*)d_in[3];
  const float* val_w = (const float*)d_in[4];
  const float* val_b = (const float*)d_in[5];
  float* out = (float*)d_out;

  char* ws = (char*)d_ws;
  __hip_bfloat16* xb = (__hip_bfloat16*)(ws);                  // 12,582,912
  __hip_bfloat16* Wall = (__hip_bfloat16*)(ws + 12582912);     //  3,538,944
  float* bias = (float*)(ws + 16121856);                       //      9,216
  __hip_bfloat16* qhead = (__hip_bfloat16*)(ws + 16131072);    // 12,582,912  [b][h][n][96]
  __hip_bfloat16* khead = (__hip_bfloat16*)(ws + 28713984);    // 12,582,912  [b][h][n][96]

  float* vout = out;                       // [8192][768] values
  float* eout = out + (size_t)M_TOT * EMB; // [64][1024][1024] energy

  prep_x_kernel<<<dim3(M_TOT * EMB / 4 / 256), dim3(256), 0, stream>>>(x, xb);
  prep_w_kernel<<<dim3(NCOLS * EMB / 256), dim3(256), 0, stream>>>(qkv_w, qkv_b, val_w, val_b,
                                                                   Wall, bias);
  gemm_kernel<<<dim3(M_TOT / 128, NCOLS / 128), dim3(256), 0, stream>>>(xb, Wall, bias, qhead,
                                                                        khead, vout);
  // ATTRIBUTION PROBE (r8-style): attn launched twice, idempotent. attn_single =
  // (total - 56.1)/2; second dispatch tops the profile -> real attn counters.
  attn_kernel<<<dim3(SEQ / 16 * NH * BATCH), dim3(512), 0, stream>>>(qhead, khead, rel, eout);
  attn_kernel<<<dim3(SEQ / 16 * NH * BATCH), dim3(512), 0, stream>>>(qhead, khead, rel, eout);
}

// Round 16
// 164.722 us; speedup vs baseline: 1.8783x; 1.8783x over previous
//
#include <hip/hip_runtime.h>
#include <hip/hip_bf16.h>

#define EMB 768
#define NH 8
#define DH 96
#define BATCH 8
#define SEQ 1024
#define M_TOT (BATCH * SEQ)   // 8192 rows of x
#define NCOLS (3 * EMB)       // q(768) | k(768) | v(768) output channels

typedef float f32x4 __attribute__((ext_vector_type(4)));
typedef __bf16 bf16x8 __attribute__((ext_vector_type(8)));

__device__ __forceinline__ unsigned short f2bf_bits(float f) {
  __hip_bfloat16 b = __float2bfloat16(f);
  return *reinterpret_cast<unsigned short*>(&b);
}

__device__ __forceinline__ void gload_lds16(const void* g, void* l) {
  // async global->LDS, 16B per lane; LDS dest is wave-uniform base (+lane*16 by HW)
  __builtin_amdgcn_global_load_lds(
      (__attribute__((address_space(1))) void*)(g),
      (__attribute__((address_space(3))) void*)(l), 16, 0, 0);
}

// ---------------- prep: x fp32 -> bf16 ----------------
__global__ void prep_x_kernel(const float* __restrict__ x, __hip_bfloat16* __restrict__ xb) {
  const int n4 = M_TOT * EMB / 4;
  int i = blockIdx.x * blockDim.x + threadIdx.x;
  if (i < n4) {
    f32x4 v = reinterpret_cast<const f32x4*>(x)[i];
    ushort4 o;
    o.x = f2bf_bits(v[0]);
    o.y = f2bf_bits(v[1]);
    o.z = f2bf_bits(v[2]);
    o.w = f2bf_bits(v[3]);
    reinterpret_cast<ushort4*>(xb)[i] = o;
  }
}

// ---------------- prep: permuted weights -> bf16, bias fp32 ----------------
__global__ void prep_w_kernel(const float* __restrict__ qkv_w, const float* __restrict__ qkv_b,
                              const float* __restrict__ val_w, const float* __restrict__ val_b,
                              __hip_bfloat16* __restrict__ Wall, float* __restrict__ bias) {
  const float inv_s = 0.03608439182435161f;  // 1/sqrt(768)
  int idx = blockIdx.x * 256 + threadIdx.x;
  if (idx >= NCOLS * EMB) return;
  int r = idx / EMB;
  int c = idx - r * EMB;
  float v;
  if (r < EMB) {
    int h = r / DH, d = r - h * DH;
    int src = h * 192 + 2 * d;
    v = qkv_w[(size_t)src * EMB + c] * inv_s;
    if (c == 0) bias[r] = qkv_b[src] * inv_s;
  } else if (r < 2 * EMB) {
    int r2 = r - EMB;
    int h = r2 / DH, d = r2 - h * DH;
    int src = h * 192 + 2 * d + 1;
    v = qkv_w[(size_t)src * EMB + c];
    if (c == 0) bias[r] = qkv_b[src];
  } else {
    int r3 = r - 2 * EMB;
    v = val_w[(size_t)r3 * EMB + c];
    if (c == 0) bias[r] = val_b[r3];
  }
  Wall[idx] = __float2bfloat16(v);
}

// ---------------- fused projection GEMM (m97-structure, 128x128, BK=32) ----------------
// Byte-identical to r11 (2D grid, plain stores; q/k via padded-LDS head-packed epilogue).
__global__ __launch_bounds__(256) void gemm_kernel(
    const __hip_bfloat16* __restrict__ xb, const __hip_bfloat16* __restrict__ Wall,
    const float* __restrict__ bias, __hip_bfloat16* __restrict__ qhead,
    __hip_bfloat16* __restrict__ khead, float* __restrict__ vout) {
  __shared__ __hip_bfloat16 As[128 * 32];
  __shared__ __hip_bfloat16 Bs[128 * 32];
  __shared__ __hip_bfloat16 Cs[128][136];  // +8 pad, rows 16B-aligned
  const int tid = threadIdx.x;
  const int w = tid >> 6, l = tid & 63;
  const int m0 = blockIdx.x * 128;
  const int n0 = blockIdx.y * 128;
  const int wr = w >> 1, wc = w & 1;

  f32x4 acc[4][4] = {};

  const int sr0 = (w * 2 + 0) * 16 + (l >> 2);
  const int sr1 = (w * 2 + 1) * 16 + (l >> 2);
  const int sc = (l & 3) * 8;

  for (int kt = 0; kt < EMB / 32; ++kt) {
    const int k0 = kt * 32;
    gload_lds16(xb + (size_t)(m0 + sr0) * EMB + k0 + sc, (void*)(As + (w * 2 + 0) * 512));
    gload_lds16(xb + (size_t)(m0 + sr1) * EMB + k0 + sc, (void*)(As + (w * 2 + 1) * 512));
    gload_lds16(Wall + (size_t)(n0 + sr0) * EMB + k0 + sc, (void*)(Bs + (w * 2 + 0) * 512));
    gload_lds16(Wall + (size_t)(n0 + sr1) * EMB + k0 + sc, (void*)(Bs + (w * 2 + 1) * 512));
    __syncthreads();

    bf16x8 af[4], bfr[4];
#pragma unroll
    for (int t = 0; t < 4; ++t) {
      af[t] = *reinterpret_cast<const bf16x8*>(As + (wr * 64 + t * 16 + (l & 15)) * 32 + (l >> 4) * 8);
      bfr[t] = *reinterpret_cast<const bf16x8*>(Bs + (wc * 64 + t * 16 + (l & 15)) * 32 + (l >> 4) * 8);
    }
#pragma unroll
    for (int i = 0; i < 4; ++i)
#pragma unroll
      for (int j = 0; j < 4; ++j)
        acc[i][j] = __builtin_amdgcn_mfma_f32_16x16x32_bf16(af[i], bfr[j], acc[i][j], 0, 0, 0);
    __syncthreads();
  }

  if (n0 >= 2 * EMB) {
    const int rowbase = m0 + wr * 64;
    const int colbase = n0 - 2 * EMB + wc * 64;
#pragma unroll
    for (int j = 0; j < 4; ++j) {
      const int n = colbase + j * 16 + (l & 15);
      const float bb = bias[2 * EMB + n];
#pragma unroll
      for (int i = 0; i < 4; ++i) {
#pragma unroll
        for (int q = 0; q < 4; ++q) {
          const int m = rowbase + i * 16 + (l >> 4) * 4 + q;
          vout[(size_t)m * EMB + n] = acc[i][j][q] + bb;
        }
      }
    }
  } else {
#pragma unroll
    for (int j = 0; j < 4; ++j) {
      const int nl = wc * 64 + j * 16 + (l & 15);
      const float bb = bias[n0 + nl];
#pragma unroll
      for (int i = 0; i < 4; ++i) {
#pragma unroll
        for (int q = 0; q < 4; ++q) {
          const int ml = wr * 64 + i * 16 + (l >> 4) * 4 + q;
          Cs[ml][nl] = __float2bfloat16(acc[i][j][q] + bb);
        }
      }
    }
    __syncthreads();
    __hip_bfloat16* dst = (n0 >= EMB) ? khead : qhead;
    const int ch0 = (n0 >= EMB) ? (n0 - EMB) : n0;
    const int cg = (tid & 15) * 8;
    const int gch = ch0 + cg;
    const int hh = gch / DH, dd = gch - hh * DH;
#pragma unroll
    for (int pass = 0; pass < 8; ++pass) {
      const int r = pass * 16 + (tid >> 4);
      const int m = m0 + r;
      const int bb_ = m >> 10, mm = m & 1023;
      bf16x8 v8 = *reinterpret_cast<const bf16x8*>(&Cs[r][cg]);
      *reinterpret_cast<bf16x8*>(dst + ((size_t)(bb_ * NH + hh) * SEQ + mm) * DH + dd) = v8;
    }
  }
}

// ---------------- fused QK^T + softmax: r11 skeleton + QROWS=32 (K chunk reused 2x) ----
// Grid 2048 (8 b-variants sharing rel rows co-XCD). 512 thr = 8 waves; block = 32 rows
// x 1024 cols; wave w owns contiguous cols [w*128, +128). Each staged K chunk feeds
// TWO 16-row tiles (qf1/qf2, acc1/acc2) -> K read traffic halved (805 -> 403 MB).
// rel loaded in-loop (2 f32x4/iter, next-chunk ahead); op-exact counted vmcnt:
// steady vmcnt(8) = st(s+1)3 + rel(s+1)2 + st(s+2)3; tail 5/0. nt stores (r15 A/B:
// nt beats plain by ~22 us). LDS 75.8 KB -> 2 blocks/CU.
__global__ __launch_bounds__(512, 4) void attn_kernel(
    const __hip_bfloat16* __restrict__ qhead, const __hip_bfloat16* __restrict__ khead,
    const float* __restrict__ rel, float* __restrict__ eout) {
  __shared__ alignas(16) char KS[8 * 3 * 3072];  // 73728 B: 8 waves x ring of 3
  __shared__ float redm[32][8];
  __shared__ float reds[32][8];

  const int t = threadIdx.x;
  const int w = t >> 6, l = t & 63;
  const int lr = l >> 4, lc = l & 15;
  // decode: flat = u*64 + b*8 + x ; g = u*8 + x -> b-variants 8 apart = same XCD
  const int flat = blockIdx.x;
  const int u = flat >> 6;           // 0..31
  const int b = (flat >> 3) & 7;
  const int g = u * 8 + (flat & 7);  // 0..255
  const int h = g >> 5;              // 0..7
  const int rb = g & 31;             // 0..31
  const int row0 = rb * 32;
  const size_t bh = (size_t)(b * NH + h);

  // ---- Q fragments for both 16-row tiles ----
  const __hip_bfloat16* qsrc = qhead + (bh * SEQ + row0 + lc) * DH;
  bf16x8 qf1[3], qf2[3];
#pragma unroll
  for (int kc = 0; kc < 3; ++kc) {
    qf1[kc] = *reinterpret_cast<const bf16x8*>(qsrc + kc * 32 + lr * 8);
    qf2[kc] = *reinterpret_cast<const bf16x8*>(qsrc + 16 * DH + kc * 32 + lr * 8);
  }

  // ---- rel chunk 0 for both tiles (rest loaded in-loop) ----
  const float* rel1 = rel + ((size_t)h * SEQ + row0 + lc) * SEQ + w * 128 + lr * 4;
  const float* rel2 = rel1 + 16 * SEQ;
  f32x4 rc1 = *reinterpret_cast<const f32x4*>(rel1);
  f32x4 rc2 = *reinterpret_cast<const f32x4*>(rel2);
  __builtin_amdgcn_sched_barrier(0);

  // ---- per-wave K staging: rows [w*128, +128), 16-row chunks of 3KB, ring-3 ----
  const __hip_bfloat16* ksrc = khead + bh * SEQ * DH + (size_t)w * 128 * DH;
  char* kdst = KS + w * 9216;

#define STAGE_K(s, buf)                                                             \
  {                                                                                 \
    const __hip_bfloat16* s_ = ksrc + (size_t)(s) * 1536 + (size_t)l * 8;           \
    gload_lds16(s_, kdst + (buf) * 3072);                                           \
    gload_lds16(s_ + 512, kdst + (buf) * 3072 + 1024);                              \
    gload_lds16(s_ + 1024, kdst + (buf) * 3072 + 2048);                             \
  }

  STAGE_K(0, 0)
  STAGE_K(1, 1)
  __builtin_amdgcn_sched_barrier(0);

  f32x4 acc1[8], acc2[8];
#pragma unroll
  for (int s = 0; s < 8; ++s) {
    // A: next chunk's rel for both tiles (2 VMEM ops)
    f32x4 rn1 = {}, rn2 = {};
    if (s < 7) {
      rn1 = *reinterpret_cast<const f32x4*>(rel1 + (s + 1) * 16);
      rn2 = *reinterpret_cast<const f32x4*>(rel2 + (s + 1) * 16);
    }
    __builtin_amdgcn_sched_barrier(0);
    // B: stage chunk s+2 (3 VMEM ops)
    if (s < 6) STAGE_K(s + 2, (s + 2) % 3)
    __builtin_amdgcn_sched_barrier(0);
    // C: counted wait for stage(s) AND rel(s)
    if (s < 6) {
      asm volatile("s_waitcnt vmcnt(8)" ::: "memory");
    } else if (s == 6) {
      asm volatile("s_waitcnt vmcnt(5)" ::: "memory");
    } else {
      asm volatile("s_waitcnt vmcnt(0)" ::: "memory");
    }
    __builtin_amdgcn_sched_barrier(0);
    const __hip_bfloat16* kp =
        reinterpret_cast<const __hip_bfloat16*>(kdst + (s % 3) * 3072) + lc * DH;
    f32x4 a1 = {0.f, 0.f, 0.f, 0.f};
    f32x4 a2 = {0.f, 0.f, 0.f, 0.f};
    __builtin_amdgcn_s_setprio(1);
#pragma unroll
    for (int kc = 0; kc < 3; ++kc) {
      bf16x8 kf = *reinterpret_cast<const bf16x8*>(kp + kc * 32 + lr * 8);
      a1 = __builtin_amdgcn_mfma_f32_16x16x32_bf16(kf, qf1[kc], a1, 0, 0, 0);
      a2 = __builtin_amdgcn_mfma_f32_16x16x32_bf16(kf, qf2[kc], a2, 0, 0, 0);
    }
    __builtin_amdgcn_s_setprio(0);
    acc1[s] = a1 + rc1;
    acc2[s] = a2 + rc2;
    if (s < 7) {
      rc1 = rn1;
      rc2 = rn2;
    }
  }
#undef STAGE_K

  // ---- softmax, both tiles (score: q-row = row0 + tile*16 + lc, col = w*128+s*16+lr*4+j) ----
  float mx1 = -3.4e38f, mx2 = -3.4e38f;
#pragma unroll
  for (int s = 0; s < 8; ++s) {
    mx1 = fmaxf(mx1, fmaxf(fmaxf(acc1[s][0], acc1[s][1]), fmaxf(acc1[s][2], acc1[s][3])));
    mx2 = fmaxf(mx2, fmaxf(fmaxf(acc2[s][0], acc2[s][1]), fmaxf(acc2[s][2], acc2[s][3])));
  }
  mx1 = fmaxf(mx1, __shfl_xor(mx1, 16));
  mx1 = fmaxf(mx1, __shfl_xor(mx1, 32));
  mx2 = fmaxf(mx2, __shfl_xor(mx2, 16));
  mx2 = fmaxf(mx2, __shfl_xor(mx2, 32));
  if (l < 16) {
    redm[lc][w] = mx1;
    redm[16 + lc][w] = mx2;
  }
  __syncthreads();
  float M1 = redm[lc][0], M2 = redm[16 + lc][0];
#pragma unroll
  for (int i = 1; i < 8; ++i) {
    M1 = fmaxf(M1, redm[lc][i]);
    M2 = fmaxf(M2, redm[16 + lc][i]);
  }

  float sm1 = 0.f, sm2 = 0.f;
#pragma unroll
  for (int s = 0; s < 8; ++s) {
#pragma unroll
    for (int j = 0; j < 4; ++j) {
      float e1 = __expf(acc1[s][j] - M1);
      float e2 = __expf(acc2[s][j] - M2);
      acc1[s][j] = e1;
      acc2[s][j] = e2;
      sm1 += e1;
      sm2 += e2;
    }
  }
  sm1 += __shfl_xor(sm1, 16);
  sm1 += __shfl_xor(sm1, 32);
  sm2 += __shfl_xor(sm2, 16);
  sm2 += __shfl_xor(sm2, 32);
  if (l < 16) {
    reds[lc][w] = sm1;
    reds[16 + lc][w] = sm2;
  }
  __syncthreads();
  float S1 = 0.f, S2 = 0.f;
#pragma unroll
  for (int i = 0; i < 8; ++i) {
    S1 += reds[lc][i];
    S2 += reds[16 + lc][i];
  }
  const float rinv1 = 1.0f / S1;
  const float rinv2 = 1.0f / S2;

  // ---- nt stores, both tiles ----
  float* op1 = eout + (bh * SEQ + row0 + lc) * SEQ + w * 128 + lr * 4;
  float* op2 = op1 + 16 * SEQ;
#pragma unroll
  for (int s = 0; s < 8; ++s) {
    f32x4 v1 = acc1[s] * rinv1;
    f32x4 v2 = acc2[s] * rinv2;
    __builtin_nontemporal_store(v1, reinterpret_cast<f32x4*>(op1 + s * 16));
    __builtin_nontemporal_store(v2, reinterpret_cast<f32x4*>(op2 + s * 16));
  }
}

extern "C" void kernel_launch(void* const* d_in, const int* in_sizes, int n_in,
                              void* d_out, int out_size, void* d_ws, size_t ws_size,
                              hipStream_t stream) {
  const float* x = (const float*)d_in[0];
  const float* rel = (const float*)d_in[1];
  const float* qkv_w = (const float*)d_in[2];
  const float* qkv_b = (const float*)d_in[3];
  const float* val_w = (const float*)d_in[4];
  const float* val_b = (const float*)d_in[5];
  float* out = (float*)d_out;

  char* ws = (char*)d_ws;
  __hip_bfloat16* xb = (__hip_bfloat16*)(ws);                  // 12,582,912
  __hip_bfloat16* Wall = (__hip_bfloat16*)(ws + 12582912);     //  3,538,944
  float* bias = (float*)(ws + 16121856);                       //      9,216
  __hip_bfloat16* qhead = (__hip_bfloat16*)(ws + 16131072);    // 12,582,912  [b][h][n][96]
  __hip_bfloat16* khead = (__hip_bfloat16*)(ws + 28713984);    // 12,582,912  [b][h][n][96]

  float* vout = out;                       // [8192][768] values
  float* eout = out + (size_t)M_TOT * EMB; // [64][1024][1024] energy

  prep_x_kernel<<<dim3(M_TOT * EMB / 4 / 256), dim3(256), 0, stream>>>(x, xb);
  prep_w_kernel<<<dim3(NCOLS * EMB / 256), dim3(256), 0, stream>>>(qkv_w, qkv_b, val_w, val_b,
                                                                   Wall, bias);
  gemm_kernel<<<dim3(M_TOT / 128, NCOLS / 128), dim3(256), 0, stream>>>(xb, Wall, bias, qhead,
                                                                        khead, vout);
  attn_kernel<<<dim3(SEQ / 32 * NH * BATCH), dim3(512), 0, stream>>>(qhead, khead, rel, eout);
}

// Round 17
// 161.382 us; speedup vs baseline: 1.9171x; 1.0207x over previous
//
#include <hip/hip_runtime.h>
#include <hip/hip_bf16.h>

#define EMB 768
#define NH 8
#define DH 96
#define BATCH 8
#define SEQ 1024
#define M_TOT (BATCH * SEQ)   // 8192 rows of x
#define NCOLS (3 * EMB)       // q(768) | k(768) | v(768) output channels

typedef float f32x4 __attribute__((ext_vector_type(4)));
typedef __bf16 bf16x8 __attribute__((ext_vector_type(8)));

__device__ __forceinline__ unsigned short f2bf_bits(float f) {
  __hip_bfloat16 b = __float2bfloat16(f);
  return *reinterpret_cast<unsigned short*>(&b);
}

__device__ __forceinline__ void gload_lds16(const void* g, void* l) {
  // async global->LDS, 16B per lane; LDS dest is wave-uniform base (+lane*16 by HW)
  __builtin_amdgcn_global_load_lds(
      (__attribute__((address_space(1))) void*)(g),
      (__attribute__((address_space(3))) void*)(l), 16, 0, 0);
}

// ---------------- prep: x fp32 -> bf16 ----------------
__global__ void prep_x_kernel(const float* __restrict__ x, __hip_bfloat16* __restrict__ xb) {
  const int n4 = M_TOT * EMB / 4;
  int i = blockIdx.x * blockDim.x + threadIdx.x;
  if (i < n4) {
    f32x4 v = reinterpret_cast<const f32x4*>(x)[i];
    ushort4 o;
    o.x = f2bf_bits(v[0]);
    o.y = f2bf_bits(v[1]);
    o.z = f2bf_bits(v[2]);
    o.w = f2bf_bits(v[3]);
    reinterpret_cast<ushort4*>(xb)[i] = o;
  }
}

// ---------------- prep: permuted weights -> bf16, bias fp32 ----------------
__global__ void prep_w_kernel(const float* __restrict__ qkv_w, const float* __restrict__ qkv_b,
                              const float* __restrict__ val_w, const float* __restrict__ val_b,
                              __hip_bfloat16* __restrict__ Wall, float* __restrict__ bias) {
  const float inv_s = 0.03608439182435161f;  // 1/sqrt(768)
  int idx = blockIdx.x * 256 + threadIdx.x;
  if (idx >= NCOLS * EMB) return;
  int r = idx / EMB;
  int c = idx - r * EMB;
  float v;
  if (r < EMB) {
    int h = r / DH, d = r - h * DH;
    int src = h * 192 + 2 * d;
    v = qkv_w[(size_t)src * EMB + c] * inv_s;
    if (c == 0) bias[r] = qkv_b[src] * inv_s;
  } else if (r < 2 * EMB) {
    int r2 = r - EMB;
    int h = r2 / DH, d = r2 - h * DH;
    int src = h * 192 + 2 * d + 1;
    v = qkv_w[(size_t)src * EMB + c];
    if (c == 0) bias[r] = qkv_b[src];
  } else {
    int r3 = r - 2 * EMB;
    v = val_w[(size_t)r3 * EMB + c];
    if (c == 0) bias[r] = val_b[r3];
  }
  Wall[idx] = __float2bfloat16(v);
}

// ---------------- fused projection GEMM (m97-structure, 128x128, BK=32) ----------------
// Byte-identical to r11 (2D grid, plain stores; q/k via padded-LDS head-packed epilogue).
__global__ __launch_bounds__(256) void gemm_kernel(
    const __hip_bfloat16* __restrict__ xb, const __hip_bfloat16* __restrict__ Wall,
    const float* __restrict__ bias, __hip_bfloat16* __restrict__ qhead,
    __hip_bfloat16* __restrict__ khead, float* __restrict__ vout) {
  __shared__ __hip_bfloat16 As[128 * 32];
  __shared__ __hip_bfloat16 Bs[128 * 32];
  __shared__ __hip_bfloat16 Cs[128][136];  // +8 pad, rows 16B-aligned
  const int tid = threadIdx.x;
  const int w = tid >> 6, l = tid & 63;
  const int m0 = blockIdx.x * 128;
  const int n0 = blockIdx.y * 128;
  const int wr = w >> 1, wc = w & 1;

  f32x4 acc[4][4] = {};

  const int sr0 = (w * 2 + 0) * 16 + (l >> 2);
  const int sr1 = (w * 2 + 1) * 16 + (l >> 2);
  const int sc = (l & 3) * 8;

  for (int kt = 0; kt < EMB / 32; ++kt) {
    const int k0 = kt * 32;
    gload_lds16(xb + (size_t)(m0 + sr0) * EMB + k0 + sc, (void*)(As + (w * 2 + 0) * 512));
    gload_lds16(xb + (size_t)(m0 + sr1) * EMB + k0 + sc, (void*)(As + (w * 2 + 1) * 512));
    gload_lds16(Wall + (size_t)(n0 + sr0) * EMB + k0 + sc, (void*)(Bs + (w * 2 + 0) * 512));
    gload_lds16(Wall + (size_t)(n0 + sr1) * EMB + k0 + sc, (void*)(Bs + (w * 2 + 1) * 512));
    __syncthreads();

    bf16x8 af[4], bfr[4];
#pragma unroll
    for (int t = 0; t < 4; ++t) {
      af[t] = *reinterpret_cast<const bf16x8*>(As + (wr * 64 + t * 16 + (l & 15)) * 32 + (l >> 4) * 8);
      bfr[t] = *reinterpret_cast<const bf16x8*>(Bs + (wc * 64 + t * 16 + (l & 15)) * 32 + (l >> 4) * 8);
    }
#pragma unroll
    for (int i = 0; i < 4; ++i)
#pragma unroll
      for (int j = 0; j < 4; ++j)
        acc[i][j] = __builtin_amdgcn_mfma_f32_16x16x32_bf16(af[i], bfr[j], acc[i][j], 0, 0, 0);
    __syncthreads();
  }

  if (n0 >= 2 * EMB) {
    const int rowbase = m0 + wr * 64;
    const int colbase = n0 - 2 * EMB + wc * 64;
#pragma unroll
    for (int j = 0; j < 4; ++j) {
      const int n = colbase + j * 16 + (l & 15);
      const float bb = bias[2 * EMB + n];
#pragma unroll
      for (int i = 0; i < 4; ++i) {
#pragma unroll
        for (int q = 0; q < 4; ++q) {
          const int m = rowbase + i * 16 + (l >> 4) * 4 + q;
          vout[(size_t)m * EMB + n] = acc[i][j][q] + bb;
        }
      }
    }
  } else {
#pragma unroll
    for (int j = 0; j < 4; ++j) {
      const int nl = wc * 64 + j * 16 + (l & 15);
      const float bb = bias[n0 + nl];
#pragma unroll
      for (int i = 0; i < 4; ++i) {
#pragma unroll
        for (int q = 0; q < 4; ++q) {
          const int ml = wr * 64 + i * 16 + (l >> 4) * 4 + q;
          Cs[ml][nl] = __float2bfloat16(acc[i][j][q] + bb);
        }
      }
    }
    __syncthreads();
    __hip_bfloat16* dst = (n0 >= EMB) ? khead : qhead;
    const int ch0 = (n0 >= EMB) ? (n0 - EMB) : n0;
    const int cg = (tid & 15) * 8;
    const int gch = ch0 + cg;
    const int hh = gch / DH, dd = gch - hh * DH;
#pragma unroll
    for (int pass = 0; pass < 8; ++pass) {
      const int r = pass * 16 + (tid >> 4);
      const int m = m0 + r;
      const int bb_ = m >> 10, mm = m & 1023;
      bf16x8 v8 = *reinterpret_cast<const bf16x8*>(&Cs[r][cg]);
      *reinterpret_cast<bf16x8*>(dst + ((size_t)(bb_ * NH + hh) * SEQ + mm) * DH + dd) = v8;
    }
  }
}

// ---------------- fused QK^T + softmax: r11 + VGPR-disciplined linear epilogue ----------------
// Grid 4096 (8 b-variants sharing rel rows co-XCD). 512 thr = 8 waves; block = 16 rows
// x 1024 cols; wave w owns contiguous cols [w*128, +128). K staged per-wave ring-3,
// counted vmcnt (q3+st0+st1 = 9 pre-loop ops -> waits 6/6/3/0 op-exact; rel NOT hoisted).
// Epilogue: raw scores transposed through the dead K-ring (row pitch 544B = 4-way max
// write conflict, no XOR needed), read back row-linear; rel loaded & added in linear
// domain (transient regs); softmax rows reduced by 5-step half-wave shfl + 2 barriers;
// nt stores as 2row x 512B runs (8 full 128B lines/instr). Epilogue txns halved vs r11.
__global__ __launch_bounds__(512, 4) void attn_kernel(
    const __hip_bfloat16* __restrict__ qhead, const __hip_bfloat16* __restrict__ khead,
    const float* __restrict__ rel, float* __restrict__ eout) {
  __shared__ alignas(16) char KS[8 * 3 * 3072];  // 73728 B: K ring; reused as transpose buf
  __shared__ float redm[16][8];
  __shared__ float reds[16][8];

  const int t = threadIdx.x;
  const int w = t >> 6, l = t & 63;
  const int lr = l >> 4, lc = l & 15;  // MFMA-domain coords
  const int rl = l >> 5, cl = l & 31;  // linear-domain coords: row-half, 16B col-group
  const int flat = blockIdx.x;
  const int u = flat >> 6;
  const int b = (flat >> 3) & 7;
  const int g = u * 8 + (flat & 7);
  const int h = g >> 6;
  const int rb = g & 63;
  const int row0 = rb * 16;
  const size_t bh = (size_t)(b * NH + h);

  // ---- Q fragments (3 VMEM ops) ----
  const __hip_bfloat16* qsrc = qhead + (bh * SEQ + row0 + lc) * DH;
  bf16x8 qf[3];
#pragma unroll
  for (int kc = 0; kc < 3; ++kc)
    qf[kc] = *reinterpret_cast<const bf16x8*>(qsrc + kc * 32 + lr * 8);

  // ---- per-wave K staging: rows [w*128, +128), 16-row chunks of 3KB, ring-3 ----
  const __hip_bfloat16* ksrc = khead + bh * SEQ * DH + (size_t)w * 128 * DH;
  char* kdst = KS + w * 9216;

#define STAGE_K(s, buf)                                                             \
  {                                                                                 \
    const __hip_bfloat16* s_ = ksrc + (size_t)(s) * 1536 + (size_t)l * 8;           \
    gload_lds16(s_, kdst + (buf) * 3072);                                           \
    gload_lds16(s_ + 512, kdst + (buf) * 3072 + 1024);                              \
    gload_lds16(s_ + 1024, kdst + (buf) * 3072 + 2048);                             \
  }

  STAGE_K(0, 0)
  STAGE_K(1, 1)
  __builtin_amdgcn_sched_barrier(0);  // pin issue order: q(3), st0(3), st1(3)

  f32x4 acc[8];
#pragma unroll
  for (int s = 0; s < 8; ++s) {
    if (s < 6) STAGE_K(s + 2, (s + 2) % 3)
    if (s < 6) {
      asm volatile("s_waitcnt vmcnt(6)" ::: "memory");  // oldest drained thru st(s); st(s+1),st(s+2) in flight
    } else if (s == 6) {
      asm volatile("s_waitcnt vmcnt(3)" ::: "memory");
    } else {
      asm volatile("s_waitcnt vmcnt(0)" ::: "memory");
    }
    __builtin_amdgcn_sched_barrier(0);
    const __hip_bfloat16* kp =
        reinterpret_cast<const __hip_bfloat16*>(kdst + (s % 3) * 3072) + lc * DH;
    f32x4 a = {0.f, 0.f, 0.f, 0.f};
    __builtin_amdgcn_s_setprio(1);
#pragma unroll
    for (int kc = 0; kc < 3; ++kc) {
      bf16x8 kf = *reinterpret_cast<const bf16x8*>(kp + kc * 32 + lr * 8);
      a = __builtin_amdgcn_mfma_f32_16x16x32_bf16(kf, qf[kc], a, 0, 0, 0);
    }
    __builtin_amdgcn_s_setprio(0);
    acc[s] = a;  // raw score; rel added in linear domain
  }
#undef STAGE_K
  asm volatile("s_waitcnt lgkmcnt(0)" ::: "memory");  // all kf reads retired: ring is dead
  __builtin_amdgcn_sched_barrier(0);

  // ---- transpose through dead ring: row pitch 544B (bank-shift 8/row, <=4-way writes) ----
  // write (row lc, byte s*64+lr*16); acc[s][j] = score(row lc, col w*128+s*16+lr*4+j)
#pragma unroll
  for (int s = 0; s < 8; ++s)
    *reinterpret_cast<f32x4*>(kdst + lc * 544 + s * 64 + lr * 16) = acc[s];
  asm volatile("s_waitcnt lgkmcnt(0)" ::: "memory");
  __builtin_amdgcn_sched_barrier(0);

  // ---- linear domain: read rows 2i+rl, add rel (transient regs) ----
  const float* relL = rel + ((size_t)h * SEQ + row0 + rl) * SEQ + w * 128 + cl * 4;
  f32x4 v[8];
#pragma unroll
  for (int i = 0; i < 8; ++i) {
    f32x4 sc = *reinterpret_cast<const f32x4*>(kdst + (2 * i + rl) * 544 + cl * 16);
    f32x4 rv = *reinterpret_cast<const f32x4*>(relL + (size_t)(2 * i) * SEQ);
    v[i] = sc + rv;
  }

  // ---- row max: in-lane 4 + 5-step half-wave shfl (rows stay within half-wave) ----
  float mx[8];
#pragma unroll
  for (int i = 0; i < 8; ++i)
    mx[i] = fmaxf(fmaxf(v[i][0], v[i][1]), fmaxf(v[i][2], v[i][3]));
#pragma unroll
  for (int d = 1; d <= 16; d <<= 1)
#pragma unroll
    for (int i = 0; i < 8; ++i) mx[i] = fmaxf(mx[i], __shfl_xor(mx[i], d));
  if (cl == 0) {
#pragma unroll
    for (int i = 0; i < 8; ++i) redm[2 * i + rl][w] = mx[i];
  }
  __syncthreads();
  float M[8];
#pragma unroll
  for (int i = 0; i < 8; ++i) {
    const float* rm = redm[2 * i + rl];
    M[i] = fmaxf(fmaxf(fmaxf(rm[0], rm[1]), fmaxf(rm[2], rm[3])),
                 fmaxf(fmaxf(rm[4], rm[5]), fmaxf(rm[6], rm[7])));
  }

  // ---- exp + row sum ----
  float sm[8];
#pragma unroll
  for (int i = 0; i < 8; ++i) {
    f32x4 e;
    e[0] = __expf(v[i][0] - M[i]);
    e[1] = __expf(v[i][1] - M[i]);
    e[2] = __expf(v[i][2] - M[i]);
    e[3] = __expf(v[i][3] - M[i]);
    v[i] = e;
    sm[i] = (e[0] + e[1]) + (e[2] + e[3]);
  }
#pragma unroll
  for (int d = 1; d <= 16; d <<= 1)
#pragma unroll
    for (int i = 0; i < 8; ++i) sm[i] += __shfl_xor(sm[i], d);
  if (cl == 0) {
#pragma unroll
    for (int i = 0; i < 8; ++i) reds[2 * i + rl][w] = sm[i];
  }
  __syncthreads();

  // ---- scale + nt stores: per instr 2 rows x 512B = 8 full 128B lines ----
  float* op = eout + (bh * SEQ + row0 + rl) * SEQ + w * 128 + cl * 4;
#pragma unroll
  for (int i = 0; i < 8; ++i) {
    const float* rs = reds[2 * i + rl];
    const float S = ((rs[0] + rs[1]) + (rs[2] + rs[3])) + ((rs[4] + rs[5]) + (rs[6] + rs[7]));
    f32x4 vv = v[i] * (1.0f / S);
    __builtin_nontemporal_store(vv, reinterpret_cast<f32x4*>(op + (size_t)(2 * i) * SEQ));
  }
}

extern "C" void kernel_launch(void* const* d_in, const int* in_sizes, int n_in,
                              void* d_out, int out_size, void* d_ws, size_t ws_size,
                              hipStream_t stream) {
  const float* x = (const float*)d_in[0];
  const float* rel = (const float*)d_in[1];
  const float* qkv_w = (const float*)d_in[2];
  const float* qkv_b = (const float*)d_in[3];
  const float* val_w = (const float*)d_in[4];
  const float* val_b = (const float*)d_in[5];
  float* out = (float*)d_out;

  char* ws = (char*)d_ws;
  __hip_bfloat16* xb = (__hip_bfloat16*)(ws);                  // 12,582,912
  __hip_bfloat16* Wall = (__hip_bfloat16*)(ws + 12582912);     //  3,538,944
  float* bias = (float*)(ws + 16121856);                       //      9,216
  __hip_bfloat16* qhead = (__hip_bfloat16*)(ws + 16131072);    // 12,582,912  [b][h][n][96]
  __hip_bfloat16* khead = (__hip_bfloat16*)(ws + 28713984);    // 12,582,912  [b][h][n][96]

  float* vout = out;                       // [8192][768] values
  float* eout = out + (size_t)M_TOT * EMB; // [64][1024][1024] energy

  prep_x_kernel<<<dim3(M_TOT * EMB / 4 / 256), dim3(256), 0, stream>>>(x, xb);
  prep_w_kernel<<<dim3(NCOLS * EMB / 256), dim3(256), 0, stream>>>(qkv_w, qkv_b, val_w, val_b,
                                                                   Wall, bias);
  gemm_kernel<<<dim3(M_TOT / 128, NCOLS / 128), dim3(256), 0, stream>>>(xb, Wall, bias, qhead,
                                                                        khead, vout);
  attn_kernel<<<dim3(SEQ / 16 * NH * BATCH), dim3(512), 0, stream>>>(qhead, khead, rel, eout);
}